// Round 6
// baseline (216.082 us; speedup 1.0000x reference)
//
#include <hip/hip_runtime.h>
#include <hip/hip_bf16.h>

#define BATCH    256
#define NU       300
#define LIN      608
#define FILT     19
#define LPOOL    84
#define POOL     7
#define HID      100
#define NCLS     50
#define EPS      1e-5f
#define KP       96    // ypool row stride (84 -> 96)
#define NP       112   // stage-2 N padded (100 -> 112)
#define LDK      104   // conv LDS row stride (shorts)
#define TCHUNK   112   // t per conv block = lcm(16,7)
#define MTN      19    // conv u-tiles (rows 0..303 cover u<300)
#define CSTR     116   // conv epilogue scratch stride (floats); (CSTR/4)%8=5 -> quad-spread

typedef __attribute__((ext_vector_type(8))) short short8;   // 8 bf16
typedef __attribute__((ext_vector_type(4))) float float4v;  // MFMA acc
typedef __attribute__((ext_vector_type(4))) unsigned short us4; // 4 bf16 out

// same-wave LDS producer->consumer ordering: lgkmcnt(0) ONLY.
#define LDS_WAIT() __asm__ __volatile__("s_waitcnt lgkmcnt(0)" ::: "memory")

__device__ __forceinline__ unsigned short f2bf(float f) {
    unsigned u = __float_as_uint(f);
    u += 0x7fffu + ((u >> 16) & 1u);       // round-to-nearest-even
    return (unsigned short)(u >> 16);
}
__device__ __forceinline__ float bf2f(unsigned short h) {
    return __uint_as_float(((unsigned)h) << 16);
}

// ---------------------------------------------------------------------------
// k_conv7d v6: SELF-CONTAINED conv(4->300,k=19)+bias+BN+exp+maxpool(7).
//   R22 theory: per-kernel roofline sum (~52us) << measured 149us => fixed
//   per-dispatch overhead dominates; k_prep is ELIMINATED (4->3 kernels).
//   Relocated work (all bit-identical math -> absmax must stay 0.125):
//   - x f32 read + f2bf(hi) INLINE in staging (xc's lo half was never read);
//   - W fragments gathered from w1 f32 via per-lane u-invariant offset
//     table; hi AND lo derived from ONE load (prep read 2 bf16 arrays);
//   - BN scale/shift (s1c1) computed inline in the epilogue (L1-hot).
//   Compute loop / epilogue / ypool [b][u][pg] layout: byte-identical to R5.
// ---------------------------------------------------------------------------
__global__ __launch_bounds__(256, 3)
void k_conv7d(const float* __restrict__ x,
              const float* __restrict__ w1,
              const float* __restrict__ b1, const float* __restrict__ g1,
              const float* __restrict__ be1, const float* __restrict__ m1,
              const float* __restrict__ v1,
              unsigned short* __restrict__ ypool)
{
    __shared__ __align__(16) unsigned short Bh[TCHUNK * LDK];  // 23296 B
    __shared__ __align__(16) float Cs[4][16 * CSTR];           // 29696 B (per-wave)

    const int tid = threadIdx.x;
    const int b   = blockIdx.x;
    const int tc  = blockIdx.y;
    const int t0  = TCHUNK * tc;
    const int NT  = (tc == 5) ? 2 : 7;         // N-tiles (t) in this block

    // ---- stage B tile (im2col, hi only), plane-major, inline f32->bf16 ----
    for (int i = tid; i < 12 * TCHUNK; i += 256) {
        const int plane = i / TCHUNK;          // 0..11 = third*4 + c
        const int trow  = i - plane * TCHUNK;
        if (trow >= 16 * NT) continue;         // unused rows (tc==5)
        const int third = plane >> 2;          // 0..2
        const int c     = plane & 3;           // 0..3
        const int kkb   = 24 * c + 8 * third;
        const int tt0   = t0 + trow + 8 * third;
        const float* src = x + ((b * 4 + c) * LIN + tt0);

        float w[8];
        if (third < 2 && tt0 + 8 <= LIN) {     // all 8 taps valid & in range
            const float4 v0 = *(const float4*)(src);
            const float4 v1 = *(const float4*)(src + 4);
            w[0] = v0.x; w[1] = v0.y; w[2] = v0.z; w[3] = v0.w;
            w[4] = v1.x; w[5] = v1.y; w[6] = v1.z; w[7] = v1.w;
        } else {
#pragma unroll
            for (int j = 0; j < 8; ++j) {
                const int tap = 8 * third + j;
                const int tt  = tt0 + j;
                float v = 0.f;
                if (tap < FILT && tt < LIN) v = src[j];
                w[j] = v;
            }
        }
        short8 hv;
#pragma unroll
        for (int j = 0; j < 8; ++j) hv[j] = (short)f2bf(w[j]);
        *(short8*)(&Bh[trow * LDK + kkb]) = hv;
    }
    __syncthreads();   // the ONLY block-wide barrier

    const int lane = tid & 63;
    const int n    = lane & 15;
    const int quad = lane >> 4;
    const int wave = tid >> 6;
    float* Csw = Cs[wave];          // wave-private transposed scratch [16][CSTR]

    const int u_l = lane & 15;      // epilogue: u row within tile
    const int wq  = lane >> 4;      // epilogue: window quad -> pg0 = 16tc+4wq
    const int pg0 = 16 * tc + 4 * wq;

    // per-lane W gather offsets (u-invariant): kk = 32s+8quad+j -> (c,tap)
    int woff[3][8];
#pragma unroll
    for (int s = 0; s < 3; ++s)
#pragma unroll
        for (int j = 0; j < 8; ++j) {
            const int kk  = 32 * s + 8 * quad + j;
            const int c   = kk / 24;
            const int tap = kk - 24 * c;
            woff[s][j] = (tap < FILT) ? (c * FILT + tap) : -1;
        }

    // inline W-fragment pack: one f32 load gives BOTH hi and lo
    auto loadW = [&](short8 (&ah)[3], short8 (&al)[3], int mt) {
        const int u = mt * 16 + n;
        const bool uv = (u < NU);
        const float* wr = w1 + u * (4 * FILT);
#pragma unroll
        for (int s = 0; s < 3; ++s)
#pragma unroll
            for (int j = 0; j < 8; ++j) {
                const int o = woff[s][j];
                float wv = (uv && o >= 0) ? wr[o] : 0.f;
                const unsigned short hi = f2bf(wv);
                ah[s][j] = (short)hi;
                al[s][j] = (short)f2bf(wv - bf2f(hi));
            }
    };

    // contiguous tile ranges: wave w owns tiles [5w, min(5w+5,19))
    const int jend = 5 * wave + ((wave == 3) ? 4 : 5);
    for (int mt0 = 5 * wave; mt0 < jend; mt0 += 2) {
        const bool two = (mt0 + 1 < jend);

        short8 a0h[3], a0l[3], a1h[3], a1l[3];
        loadW(a0h, a0l, mt0);
        loadW(a1h, a1l, two ? (mt0 + 1) : mt0);

        // ---- main loop: xh-frags read once per nt, used by BOTH tiles ----
        // SWAPPED operands: acc = x_tile(16t x 32k) * W^T(32k x 16u) -> D[t][u]
        float4v acc[2][7];
#pragma unroll
        for (int t2 = 0; t2 < 2; ++t2)
#pragma unroll
            for (int nt = 0; nt < 7; ++nt)
                acc[t2][nt] = (float4v){0.f, 0.f, 0.f, 0.f};

#pragma unroll
        for (int nt = 0; nt < 7; ++nt) {
            if (nt < NT) {
                short8 bhf[3];
#pragma unroll
                for (int s = 0; s < 3; ++s)
                    bhf[s] = *(const short8*)(&Bh[(16 * nt + n) * LDK + 32 * s + 8 * quad]);
#pragma unroll
                for (int s = 0; s < 3; ++s)
                    acc[0][nt] = __builtin_amdgcn_mfma_f32_16x16x32_bf16(
                        bhf[s], a0h[s], acc[0][nt], 0, 0, 0);
#pragma unroll
                for (int s = 0; s < 3; ++s)
                    acc[0][nt] = __builtin_amdgcn_mfma_f32_16x16x32_bf16(
                        bhf[s], a0l[s], acc[0][nt], 0, 0, 0);
                if (two) {
#pragma unroll
                    for (int s = 0; s < 3; ++s)
                        acc[1][nt] = __builtin_amdgcn_mfma_f32_16x16x32_bf16(
                            bhf[s], a1h[s], acc[1][nt], 0, 0, 0);
#pragma unroll
                    for (int s = 0; s < 3; ++s)
                        acc[1][nt] = __builtin_amdgcn_mfma_f32_16x16x32_bf16(
                            bhf[s], a1l[s], acc[1][nt], 0, 0, 0);
                }
            }
        }

        // ---- wave-local epilogue per tile: write Cs, b128 reads, 8B store ----
#pragma unroll
        for (int t2 = 0; t2 < 2; ++t2) {
            if (t2 == 1 && !two) break;
            const int mt = mt0 + t2;

            LDS_WAIT();   // WAR: previous tile's pool reads complete
#pragma unroll
            for (int nt = 0; nt < 7; ++nt) {
                if (nt < NT)
                    *(float4v*)(&Csw[n * CSTR + 16 * nt + 4 * quad]) = acc[t2][nt];
            }
            LDS_WAIT();   // RAW: writes visible to all lanes of this wave

            // lane (u_l, wq): read 28-float span t=[28wq, 28wq+28) of row u_l
            float rv[28];
#pragma unroll
            for (int r7 = 0; r7 < 7; ++r7)
                *(float4v*)(&rv[4 * r7]) =
                    *(const float4v*)(&Csw[u_l * CSTR + 28 * wq + 4 * r7]);

            const int uglob = mt * 16 + u_l;
            float scx = 0.f, scy = 0.f;
            if (uglob < NU) {                  // inline BN scale/shift (L1-hot)
                const float s1 = g1[uglob] * rsqrtf(v1[uglob] + EPS);
                scx = s1;
                scy = (b1[uglob] - m1[uglob]) * s1 + be1[uglob];
            }
            us4 pk;
#pragma unroll
            for (int w4 = 0; w4 < 4; ++w4) {
                const int pg = pg0 + w4;
                unsigned short ov = 0;
                if (pg < LPOOL) {
                    float m0 = fmaxf(rv[7 * w4 + 0], rv[7 * w4 + 1]);
                    float m1x = fmaxf(rv[7 * w4 + 2], rv[7 * w4 + 3]);
                    float m2 = fmaxf(rv[7 * w4 + 4], rv[7 * w4 + 5]);
                    m0 = fmaxf(m0, rv[7 * w4 + 6]);
                    ov = f2bf(__expf(fmaf(fmaxf(fmaxf(m0, m1x), m2), scx, scy)));
                }
                pk[w4] = ov;
            }
            if (uglob < NU)
                *(us4*)(&ypool[((size_t)b * NU + uglob) * KP + pg0]) = pk;
        }
    }
}

// ---------------------------------------------------------------------------
// k_mlp v7: SELF-CONTAINED — reads w2 f32 directly with inline f2bf (kills
//   the w2c precompute). Grid (300,1): 4 batch-groups per wave => all 300
//   blocks co-resident (no rounds), af loaded once per mt feeds 4 MFMAs.
//   w2 read ~once from HBM (10 MB, ~1.7us floor). Math identical to R5.
// ---------------------------------------------------------------------------
__global__ __launch_bounds__(256, 4)
void k_mlp(const unsigned short* __restrict__ ypool,
           const float* __restrict__ w2,
           const float* __restrict__ g2, const float* __restrict__ b2,
           const float* __restrict__ be2, const float* __restrict__ m2,
           const float* __restrict__ v2,
           const float* __restrict__ w3, const float* __restrict__ b3,
           const float* __restrict__ g3, const float* __restrict__ be3,
           const float* __restrict__ m3, const float* __restrict__ v3,
           float* __restrict__ zbuf)
{
    __shared__ __align__(16) float4 cs4[NP];                // (s2,c2,w3,0)

    const int tid = threadIdx.x;
    const int u   = blockIdx.x;

    if (tid < NP) {
        float4 cv = {0.f, 0.f, 0.f, 0.f};
        if (tid < HID) {
            const int uo = u * HID + tid;
            const float s = g2[uo] * rsqrtf(v2[uo] + EPS);
            cv.x = s;
            cv.y = (b2[uo] - m2[uo]) * s + be2[uo];
            cv.z = w3[uo];
        }
        cs4[tid] = cv;
    }
    __syncthreads();

    const int lane = tid & 63;
    const int wave = tid >> 6;
    const int col  = lane & 15;
    const int quad = lane >> 4;

    // B fragments for 4 batch groups (192 B rows, read once)
    short8 bf_[4][3];
#pragma unroll
    for (int g = 0; g < 4; ++g) {
        const int bb = 64 * g + 16 * wave + col;
        const unsigned short* yr = ypool + ((size_t)bb * NU + u) * KP;
#pragma unroll
        for (int s = 0; s < 3; ++s)
            bf_[g][s] = *(const short8*)(yr + 32 * s + 8 * quad);
    }

    const float* wb = w2 + (size_t)u * HID * LPOOL;
    float zp[4] = {0.f, 0.f, 0.f, 0.f};
#pragma unroll
    for (int mt = 0; mt < 7; ++mt) {
        const int o = 16 * mt + col;
        short8 af[3];
        if (o < HID) {
            const float* row = wb + o * LPOOL;
#pragma unroll
            for (int s = 0; s < 3; ++s) {
                const int kk0 = 32 * s + 8 * quad;
                float v[8];
                if (kk0 <= 76) {               // all 8 cols < 84
                    const float4 p0 = *(const float4*)(row + kk0);
                    const float4 p1 = *(const float4*)(row + kk0 + 4);
                    v[0] = p0.x; v[1] = p0.y; v[2] = p0.z; v[3] = p0.w;
                    v[4] = p1.x; v[5] = p1.y; v[6] = p1.z; v[7] = p1.w;
                } else if (kk0 == 80) {        // cols 80..83 valid
                    const float4 p0 = *(const float4*)(row + 80);
                    v[0] = p0.x; v[1] = p0.y; v[2] = p0.z; v[3] = p0.w;
                    v[4] = 0.f; v[5] = 0.f; v[6] = 0.f; v[7] = 0.f;
                } else {                       // kk0 == 88: k-pad
#pragma unroll
                    for (int j = 0; j < 8; ++j) v[j] = 0.f;
                }
#pragma unroll
                for (int j = 0; j < 8; ++j) af[s][j] = (short)f2bf(v[j]);
            }
        } else {                               // o-pad rows (>= HID)
#pragma unroll
            for (int s = 0; s < 3; ++s)
#pragma unroll
                for (int j = 0; j < 8; ++j) af[s][j] = 0;
        }

        float4v a[4];
#pragma unroll
        for (int g = 0; g < 4; ++g) a[g] = (float4v){0.f, 0.f, 0.f, 0.f};
#pragma unroll
        for (int s = 0; s < 3; ++s)
#pragma unroll
            for (int g = 0; g < 4; ++g)
                a[g] = __builtin_amdgcn_mfma_f32_16x16x32_bf16(af[s], bf_[g][s], a[g], 0, 0, 0);
#pragma unroll
        for (int r = 0; r < 4; ++r) {
            const float4 cv = cs4[16 * mt + 4 * quad + r];
#pragma unroll
            for (int g = 0; g < 4; ++g)
                zp[g] = fmaf(fmaxf(fmaf(a[g][r], cv.x, cv.y), 0.f), cv.z, zp[g]);
        }
    }

#pragma unroll
    for (int g = 0; g < 4; ++g) {
        zp[g] += __shfl_xor(zp[g], 16);
        zp[g] += __shfl_xor(zp[g], 32);
    }

    if (quad == 0) {
        const float s3 = g3[u] * rsqrtf(v3[u] + EPS);
        const float c3 = (b3[u] - m3[u]) * s3 + be3[u];
#pragma unroll
        for (int g = 0; g < 4; ++g) {
            const int bb = 64 * g + 16 * wave + col;
            zbuf[(size_t)u * BATCH + bb] = fmaxf(fmaf(zp[g], s3, c3), 0.f);
        }
    }
}

// ---------------------------------------------------------------------------
// k_final v2: (byte-identical to R11-R22)
// ---------------------------------------------------------------------------
__global__ __launch_bounds__(256, 4)
void k_final(const float* __restrict__ zbuf, const float* __restrict__ wf,
             const float* __restrict__ bf, float* __restrict__ out)
{
    __shared__ float red[4][64];
    const int nc   = blockIdx.x;
    const int bq   = blockIdx.y;
    const int lane = threadIdx.x & 63;
    const int wave = threadIdx.x >> 6;
    const int b    = bq * 64 + lane;

    float a0 = 0.f, a1 = 0.f, a2 = 0.f;
    const int u0 = wave * 75;
#pragma unroll 5
    for (int i = 0; i < 75; i += 3) {
        a0 = fmaf(zbuf[(size_t)(u0 + i + 0) * BATCH + b], wf[nc * NU + u0 + i + 0], a0);
        a1 = fmaf(zbuf[(size_t)(u0 + i + 1) * BATCH + b], wf[nc * NU + u0 + i + 1], a1);
        a2 = fmaf(zbuf[(size_t)(u0 + i + 2) * BATCH + b], wf[nc * NU + u0 + i + 2], a2);
    }
    red[wave][lane] = (a0 + a1) + a2;
    __syncthreads();
    if (threadIdx.x < 64) {
        const float s = (red[0][lane] + red[1][lane]) + (red[2][lane] + red[3][lane]);
        out[(size_t)b * NCLS + nc] = s + bf[nc];
    }
}

extern "C" void kernel_launch(void* const* d_in, const int* in_sizes, int n_in,
                              void* d_out, int out_size, void* d_ws, size_t ws_size,
                              hipStream_t stream)
{
    const float* x   = (const float*)d_in[0];
    const float* w1  = (const float*)d_in[1];
    const float* b1  = (const float*)d_in[2];
    const float* g1  = (const float*)d_in[3];
    const float* be1 = (const float*)d_in[4];
    const float* m1  = (const float*)d_in[5];
    const float* v1  = (const float*)d_in[6];
    const float* w2  = (const float*)d_in[7];
    const float* b2  = (const float*)d_in[8];
    const float* g2  = (const float*)d_in[9];
    const float* be2 = (const float*)d_in[10];
    const float* m2  = (const float*)d_in[11];
    const float* v2  = (const float*)d_in[12];
    const float* w3  = (const float*)d_in[13];
    const float* b3  = (const float*)d_in[14];
    const float* g3  = (const float*)d_in[15];
    const float* be3 = (const float*)d_in[16];
    const float* m3  = (const float*)d_in[17];
    const float* v3  = (const float*)d_in[18];
    const float* wf  = (const float*)d_in[19];
    const float* bf  = (const float*)d_in[20];

    // workspace layout (bytes):
    //   ypool  bf16 [256][300][96]  @ 0          (14,745,600)   [b][u][pg]
    //   zbuf   f32  [300][256]      @ 14,745,600 (307,200)
    unsigned short* ypool = (unsigned short*)d_ws;
    float* zbuf = (float*)((char*)d_ws + 14745600);

    dim3 gc(BATCH, 6);
    k_conv7d<<<gc, 256, 0, stream>>>(x, w1, b1, g1, be1, m1, v1, ypool);

    k_mlp<<<NU, 256, 0, stream>>>(ypool, w2, g2, b2, be2, m2, v2,
                                  w3, b3, g3, be3, m3, v3, zbuf);

    dim3 gf(NCLS, 4);
    k_final<<<gf, 256, 0, stream>>>(zbuf, wf, bf, (float*)d_out);
}

// Round 7
// 153.296 us; speedup vs baseline: 1.4096x; 1.4096x over previous
//
#include <hip/hip_runtime.h>
#include <hip/hip_bf16.h>

#define BATCH    256
#define NU       300
#define LIN      608
#define FILT     19
#define LPOOL    84
#define POOL     7
#define HID      100
#define NCLS     50
#define EPS      1e-5f
#define KP       96    // ypool row stride (84 -> 96)
#define NP       112   // stage-2 N padded (100 -> 112)
#define LDK      104   // conv LDS row stride (shorts)
#define LDKW     96    // w2c row stride (shorts)
#define WROW     104   // packed-W row stride (shorts)
#define WBROWS   320   // packed-W rows (300 + pad)
#define TCHUNK   112   // t per conv block = lcm(16,7)
#define MTN      19    // conv u-tiles (rows 0..303 cover u<300)
#define CSTR     116   // conv epilogue scratch stride (floats); (CSTR/4)%8=5 -> quad-spread

typedef __attribute__((ext_vector_type(8))) short short8;   // 8 bf16
typedef __attribute__((ext_vector_type(4))) float float4v;  // MFMA acc
typedef __attribute__((ext_vector_type(4))) unsigned short us4; // 4 bf16 out

// same-wave LDS producer->consumer ordering: lgkmcnt(0) ONLY.
#define LDS_WAIT() __asm__ __volatile__("s_waitcnt lgkmcnt(0)" ::: "memory")

__device__ __forceinline__ unsigned short f2bf(float f) {
    unsigned u = __float_as_uint(f);
    u += 0x7fffu + ((u >> 16) & 1u);       // round-to-nearest-even
    return (unsigned short)(u >> 16);
}
__device__ __forceinline__ float bf2f(unsigned short h) {
    return __uint_as_float(((unsigned)h) << 16);
}

// ---------------------------------------------------------------------------
// k_prep v3: (byte-identical to R5 — verified at 149.1)
// ---------------------------------------------------------------------------
__global__ void k_prep(const float* __restrict__ w1, const float* __restrict__ x,
                       const float* __restrict__ b1, const float* __restrict__ g1,
                       const float* __restrict__ be1, const float* __restrict__ m1,
                       const float* __restrict__ v1, const float* __restrict__ w2,
                       unsigned short* __restrict__ Wbh,
                       unsigned short* __restrict__ Wbl,
                       unsigned int* __restrict__ xc,
                       float2* __restrict__ s1c1,
                       unsigned short* __restrict__ w2c)
{
    const int idx = blockIdx.x * 256 + threadIdx.x;
    const int NW = WBROWS * WROW;               // 33280
    if (idx < NW) {
        const int u = idx / WROW, kk = idx - u * WROW;
        float wv = 0.f;
        if (u < NU && kk < 96) {
            const int c = kk / 24, tap = kk - 24 * c;
            if (tap < FILT) wv = w1[(u * 4 + c) * FILT + tap];
        }
        const unsigned short hi = f2bf(wv);
        Wbh[idx] = hi;
        Wbl[idx] = f2bf(wv - bf2f(hi));
    }
    const int j = idx - NW;
    if (j >= 0 && j < BATCH * 4 * LIN) {
        const float xv = x[j];
        const unsigned short hi = f2bf(xv);
        const unsigned short lo = f2bf(xv - bf2f(hi));
        xc[j] = (unsigned)hi | ((unsigned)lo << 16);
    }
    const int j2 = j - BATCH * 4 * LIN;
    if (j2 >= 0 && j2 < MTN * 16) {
        float2 v = {0.f, 0.f};
        if (j2 < NU) {
            const float s = g1[j2] * rsqrtf(v1[j2] + EPS);
            v.x = s;
            v.y = (b1[j2] - m1[j2]) * s + be1[j2];
        }
        s1c1[j2] = v;
    }
    const int j3 = j2 - MTN * 16;
    if (j3 >= 0 && j3 < NU * NP * LDKW) {
        const int u  = j3 / (NP * LDKW);
        const int r  = j3 - u * (NP * LDKW);
        const int o  = r / LDKW;
        const int kc = r - o * LDKW;
        float wv = 0.f;
        if (o < HID && kc < LPOOL) wv = w2[((size_t)u * HID + o) * LPOOL + kc];
        w2c[j3] = f2bf(wv);
    }
}

// ---------------------------------------------------------------------------
// k_conv7d v8: R5's verified v5 restructured for residency/chain-length.
//   R6 lesson (counters): inline-W gather was the regression (VALU 33%,
//   Mfma 8.5%) — REVERTED to prep-packed Wbh/Wbl. New time model (fits R5
//   AND R6 exactly): ~88us poison fills are fixed; conv (~40us) is 2/3 of
//   the controllable 61us. Conv does ~7us of pipe work in 40us => chain-
//   latency x thin residency. THIS round, work-conserving restructure:
//   - 512 threads / 8 waves per block, same grid (256,6), same 19 tiles
//     per block => per-wave chain 2-3 tiles (was 4-5), staging rounds
//     5.25 -> 2.6, waves/CU 12 -> 16-24.
//   - Cs halved to 8 u-rows/wave ([8][CSTR]); epilogue per tile runs two
//     halves (write 8 rows, pool+store by the matching 32 lanes). LDS
//     total 52,992 B => 3 blocks/CU at <=85 VGPR, 2 otherwise.
//   Total MFMA / Bh-read / W-load volume UNCHANGED (11 load-units).
// ---------------------------------------------------------------------------
__global__ __launch_bounds__(512, 4)
void k_conv7d(const unsigned short* __restrict__ Wbh,
              const unsigned short* __restrict__ Wbl,
              const unsigned int* __restrict__ xc,
              const float2* __restrict__ s1c1,
              unsigned short* __restrict__ ypool)
{
    __shared__ __align__(16) unsigned short Bh[TCHUNK * LDK];  // 23296 B
    __shared__ __align__(16) float Cs[8][8 * CSTR];            // 29696 B (per-wave)

    const int tid = threadIdx.x;
    const int b   = blockIdx.x;
    const int tc  = blockIdx.y;
    const int t0  = TCHUNK * tc;
    const int NT  = (tc == 5) ? 2 : 7;         // N-tiles (t) in this block

    // ---- stage B tile (im2col, hi only), plane-major (R5 mapping) ----
    for (int i = tid; i < 12 * TCHUNK; i += 512) {
        const int plane = i / TCHUNK;          // 0..11 = third*4 + c
        const int trow  = i - plane * TCHUNK;
        if (trow >= 16 * NT) continue;         // unused rows (tc==5)
        const int third = plane >> 2;          // 0..2
        const int c     = plane & 3;           // 0..3
        const int kkb   = 24 * c + 8 * third;
        const int tt0   = t0 + trow + 8 * third;
        const unsigned int* src = xc + ((b * 4 + c) * LIN + tt0);

        unsigned int w[8];
        if (third < 2 && tt0 + 8 <= LIN) {     // all 8 taps valid & in range
            const uint4 v0 = *(const uint4*)(src);
            const uint4 v1 = *(const uint4*)(src + 4);
            w[0] = v0.x; w[1] = v0.y; w[2] = v0.z; w[3] = v0.w;
            w[4] = v1.x; w[5] = v1.y; w[6] = v1.z; w[7] = v1.w;
        } else {
#pragma unroll
            for (int j = 0; j < 8; ++j) {
                const int tap = 8 * third + j;
                const int tt  = tt0 + j;
                unsigned int v = 0;
                if (tap < FILT && tt < LIN) v = src[j];
                w[j] = v;
            }
        }
        short8 hv;
#pragma unroll
        for (int j = 0; j < 8; ++j) hv[j] = (short)(w[j] & 0xffffu);
        *(short8*)(&Bh[trow * LDK + kkb]) = hv;
    }
    __syncthreads();   // the ONLY block-wide barrier

    const int lane = tid & 63;
    const int n    = lane & 15;
    const int quad = lane >> 4;
    const int wave = tid >> 6;                 // 0..7
    float* Csw = Cs[wave];          // wave-private transposed scratch [8][CSTR]

    const int u_l = lane & 15;      // epilogue: u row within tile
    const int wq  = lane >> 4;      // epilogue: window quad -> pg0 = 16tc+4wq
    const int pg0 = 16 * tc + 4 * wq;

    // tile ranges over 8 waves: w0-2 own 3 tiles, w3-7 own 2  (3*3+5*2=19)
    const int ts   = (wave < 3) ? 3 * wave : 9 + 2 * (wave - 3);
    const int tend = ts + ((wave < 3) ? 3 : 2);

    for (int mt0 = ts; mt0 < tend; mt0 += 2) {
        const bool two = (mt0 + 1 < tend);

        // ---- W fragments (hi & lo) for both tiles, from global (L2-hot) ----
        short8 a0h[3], a0l[3], a1h[3], a1l[3];
        {
            const unsigned short* wrh = Wbh + (size_t)(mt0 * 16 + n) * WROW;
            const unsigned short* wrl = Wbl + (size_t)(mt0 * 16 + n) * WROW;
#pragma unroll
            for (int s = 0; s < 3; ++s) {
                a0h[s] = *(const short8*)(wrh + 32 * s + 8 * quad);
                a0l[s] = *(const short8*)(wrl + 32 * s + 8 * quad);
            }
            const int m1r = two ? (mt0 + 1) : mt0;
            const unsigned short* wrh1 = Wbh + (size_t)(m1r * 16 + n) * WROW;
            const unsigned short* wrl1 = Wbl + (size_t)(m1r * 16 + n) * WROW;
#pragma unroll
            for (int s = 0; s < 3; ++s) {
                a1h[s] = *(const short8*)(wrh1 + 32 * s + 8 * quad);
                a1l[s] = *(const short8*)(wrl1 + 32 * s + 8 * quad);
            }
        }

        // ---- main loop: xh-frags read once per nt, used by BOTH tiles ----
        // SWAPPED operands: acc = x_tile(16t x 32k) * W^T(32k x 16u) -> D[t][u]
        float4v acc[2][7];
#pragma unroll
        for (int t2 = 0; t2 < 2; ++t2)
#pragma unroll
            for (int nt = 0; nt < 7; ++nt)
                acc[t2][nt] = (float4v){0.f, 0.f, 0.f, 0.f};

#pragma unroll
        for (int nt = 0; nt < 7; ++nt) {
            if (nt < NT) {
                short8 bhf[3];
#pragma unroll
                for (int s = 0; s < 3; ++s)
                    bhf[s] = *(const short8*)(&Bh[(16 * nt + n) * LDK + 32 * s + 8 * quad]);
#pragma unroll
                for (int s = 0; s < 3; ++s)
                    acc[0][nt] = __builtin_amdgcn_mfma_f32_16x16x32_bf16(
                        bhf[s], a0h[s], acc[0][nt], 0, 0, 0);
#pragma unroll
                for (int s = 0; s < 3; ++s)
                    acc[0][nt] = __builtin_amdgcn_mfma_f32_16x16x32_bf16(
                        bhf[s], a0l[s], acc[0][nt], 0, 0, 0);
                if (two) {
#pragma unroll
                    for (int s = 0; s < 3; ++s)
                        acc[1][nt] = __builtin_amdgcn_mfma_f32_16x16x32_bf16(
                            bhf[s], a1h[s], acc[1][nt], 0, 0, 0);
#pragma unroll
                    for (int s = 0; s < 3; ++s)
                        acc[1][nt] = __builtin_amdgcn_mfma_f32_16x16x32_bf16(
                            bhf[s], a1l[s], acc[1][nt], 0, 0, 0);
                }
            }
        }

        // ---- wave-local epilogue per tile: two 8-u-row halves ----
#pragma unroll
        for (int t2 = 0; t2 < 2; ++t2) {
            if (t2 == 1 && !two) break;
            const int mt    = mt0 + t2;
            const int uglob = mt * 16 + u_l;
            const float2 sc = s1c1[uglob];     // s1c1 sized 304 >= max uglob+1

#pragma unroll
            for (int h = 0; h < 2; ++h) {
                LDS_WAIT();   // WAR: prior reads of these rows complete
                if ((n >> 3) == h) {
#pragma unroll
                    for (int nt = 0; nt < 7; ++nt)
                        if (nt < NT)
                            *(float4v*)(&Csw[(n & 7) * CSTR + 16 * nt + 4 * quad]) = acc[t2][nt];
                }
                LDS_WAIT();   // RAW: writes visible to all lanes of this wave

                if ((u_l >> 3) == h) {
                    // lane (u_l, wq): 28-float span t=[28wq, 28wq+28) of row u_l&7
                    float rv[28];
#pragma unroll
                    for (int r7 = 0; r7 < 7; ++r7)
                        *(float4v*)(&rv[4 * r7]) =
                            *(const float4v*)(&Csw[(u_l & 7) * CSTR + 28 * wq + 4 * r7]);

                    us4 pk;
#pragma unroll
                    for (int w4 = 0; w4 < 4; ++w4) {
                        const int pg = pg0 + w4;
                        unsigned short ov = 0;
                        if (pg < LPOOL) {
                            float m0 = fmaxf(rv[7 * w4 + 0], rv[7 * w4 + 1]);
                            float m1 = fmaxf(rv[7 * w4 + 2], rv[7 * w4 + 3]);
                            float m2 = fmaxf(rv[7 * w4 + 4], rv[7 * w4 + 5]);
                            m0 = fmaxf(m0, rv[7 * w4 + 6]);
                            ov = f2bf(__expf(fmaf(fmaxf(fmaxf(m0, m1), m2), sc.x, sc.y)));
                        }
                        pk[w4] = ov;
                    }
                    if (uglob < NU)
                        *(us4*)(&ypool[((size_t)b * NU + uglob) * KP + pg0]) = pk;
                }
            }
        }
    }
}

// ---------------------------------------------------------------------------
// k_mlp v6: (byte-identical to R5 — verified at 149.1)
// ---------------------------------------------------------------------------
__global__ __launch_bounds__(256, 4)
void k_mlp(const unsigned short* __restrict__ ypool,
           const unsigned short* __restrict__ w2c,
           const float* __restrict__ g2, const float* __restrict__ b2,
           const float* __restrict__ be2, const float* __restrict__ m2,
           const float* __restrict__ v2,
           const float* __restrict__ w3, const float* __restrict__ b3,
           const float* __restrict__ g3, const float* __restrict__ be3,
           const float* __restrict__ m3, const float* __restrict__ v3,
           float* __restrict__ zbuf)
{
    __shared__ __align__(16) float4 cs4[NP];                // (s2,c2,w3,0)

    const int tid = threadIdx.x;
    const int u   = blockIdx.x;
    const int b0  = blockIdx.y * 128;

    if (tid < NP) {
        float4 cv = {0.f, 0.f, 0.f, 0.f};
        if (tid < HID) {
            const int uo = u * HID + tid;
            const float s = g2[uo] * rsqrtf(v2[uo] + EPS);
            cv.x = s;
            cv.y = (b2[uo] - m2[uo]) * s + be2[uo];
            cv.z = w3[uo];
        }
        cs4[tid] = cv;
    }
    __syncthreads();

    const int lane = tid & 63;
    const int wave = tid >> 6;
    const int col  = lane & 15;
    const int quad = lane >> 4;
    const int bbA  = b0 + 16 * wave + col;          // batch group 0
    const int bbB  = bbA + 64;                       // batch group 1

    // B fragments for both batch groups (192 B rows, read once)
    short8 bfA[3], bfB[3];
    {
        const unsigned short* yrA = ypool + ((size_t)bbA * NU + u) * KP;
        const unsigned short* yrB = ypool + ((size_t)bbB * NU + u) * KP;
#pragma unroll
        for (int s = 0; s < 3; ++s) {
            bfA[s] = *(const short8*)(yrA + 32 * s + 8 * quad);
            bfB[s] = *(const short8*)(yrB + 32 * s + 8 * quad);
        }
    }

    const unsigned short* wbase = w2c + (size_t)u * (NP * LDKW);
    float zpA = 0.f, zpB = 0.f;
#pragma unroll
    for (int mt = 0; mt < 7; ++mt) {
        short8 af[3];
#pragma unroll
        for (int s = 0; s < 3; ++s)
            af[s] = *(const short8*)(wbase + (16 * mt + col) * LDKW + 32 * s + 8 * quad);

        float4v a0 = {0.f, 0.f, 0.f, 0.f}, a1 = {0.f, 0.f, 0.f, 0.f};
#pragma unroll
        for (int s = 0; s < 3; ++s) {
            a0 = __builtin_amdgcn_mfma_f32_16x16x32_bf16(af[s], bfA[s], a0, 0, 0, 0);
            a1 = __builtin_amdgcn_mfma_f32_16x16x32_bf16(af[s], bfB[s], a1, 0, 0, 0);
        }
#pragma unroll
        for (int r = 0; r < 4; ++r) {
            const float4 cv = cs4[16 * mt + 4 * quad + r];
            zpA = fmaf(fmaxf(fmaf(a0[r], cv.x, cv.y), 0.f), cv.z, zpA);
            zpB = fmaf(fmaxf(fmaf(a1[r], cv.x, cv.y), 0.f), cv.z, zpB);
        }
    }

    zpA += __shfl_xor(zpA, 16); zpA += __shfl_xor(zpA, 32);
    zpB += __shfl_xor(zpB, 16); zpB += __shfl_xor(zpB, 32);

    if (quad == 0) {
        const float s3 = g3[u] * rsqrtf(v3[u] + EPS);
        const float c3 = (b3[u] - m3[u]) * s3 + be3[u];
        zbuf[(size_t)u * BATCH + bbA] = fmaxf(fmaf(zpA, s3, c3), 0.f);
        zbuf[(size_t)u * BATCH + bbB] = fmaxf(fmaf(zpB, s3, c3), 0.f);
    }
}

// ---------------------------------------------------------------------------
// k_final v2: (byte-identical to R11-R23)
// ---------------------------------------------------------------------------
__global__ __launch_bounds__(256, 4)
void k_final(const float* __restrict__ zbuf, const float* __restrict__ wf,
             const float* __restrict__ bf, float* __restrict__ out)
{
    __shared__ float red[4][64];
    const int nc   = blockIdx.x;
    const int bq   = blockIdx.y;
    const int lane = threadIdx.x & 63;
    const int wave = threadIdx.x >> 6;
    const int b    = bq * 64 + lane;

    float a0 = 0.f, a1 = 0.f, a2 = 0.f;
    const int u0 = wave * 75;
#pragma unroll 5
    for (int i = 0; i < 75; i += 3) {
        a0 = fmaf(zbuf[(size_t)(u0 + i + 0) * BATCH + b], wf[nc * NU + u0 + i + 0], a0);
        a1 = fmaf(zbuf[(size_t)(u0 + i + 1) * BATCH + b], wf[nc * NU + u0 + i + 1], a1);
        a2 = fmaf(zbuf[(size_t)(u0 + i + 2) * BATCH + b], wf[nc * NU + u0 + i + 2], a2);
    }
    red[wave][lane] = (a0 + a1) + a2;
    __syncthreads();
    if (threadIdx.x < 64) {
        const float s = (red[0][lane] + red[1][lane]) + (red[2][lane] + red[3][lane]);
        out[(size_t)b * NCLS + nc] = s + bf[nc];
    }
}

extern "C" void kernel_launch(void* const* d_in, const int* in_sizes, int n_in,
                              void* d_out, int out_size, void* d_ws, size_t ws_size,
                              hipStream_t stream)
{
    const float* x   = (const float*)d_in[0];
    const float* w1  = (const float*)d_in[1];
    const float* b1  = (const float*)d_in[2];
    const float* g1  = (const float*)d_in[3];
    const float* be1 = (const float*)d_in[4];
    const float* m1  = (const float*)d_in[5];
    const float* v1  = (const float*)d_in[6];
    const float* w2  = (const float*)d_in[7];
    const float* b2  = (const float*)d_in[8];
    const float* g2  = (const float*)d_in[9];
    const float* be2 = (const float*)d_in[10];
    const float* m2  = (const float*)d_in[11];
    const float* v2  = (const float*)d_in[12];
    const float* w3  = (const float*)d_in[13];
    const float* b3  = (const float*)d_in[14];
    const float* g3  = (const float*)d_in[15];
    const float* be3 = (const float*)d_in[16];
    const float* m3  = (const float*)d_in[17];
    const float* v3  = (const float*)d_in[18];
    const float* wf  = (const float*)d_in[19];
    const float* bf  = (const float*)d_in[20];

    // workspace layout (bytes):
    //   ypool  bf16 [256][300][96]  @ 0          (14,745,600)   [b][u][pg]
    //   zbuf   f32  [300][256]      @ 14,745,600 (307,200)
    //   Wbh    bf16 [320][104]      @ 15,052,800 (66,560)
    //   Wbl    bf16 [320][104]      @ 15,119,360 (66,560)
    //   xc     u32  [256][4][608]   @ 15,185,920 (2,490,368)
    //   s1c1   f32x2 [304]          @ 17,676,288 (2,432)
    //   w2c    bf16 [300][112][96]  @ 17,678,720 (6,451,200)
    unsigned short* ypool = (unsigned short*)d_ws;
    float* zbuf = (float*)((char*)d_ws + 14745600);
    unsigned short* Wbh = (unsigned short*)((char*)d_ws + 15052800);
    unsigned short* Wbl = (unsigned short*)((char*)d_ws + 15119360);
    unsigned int*   xc  = (unsigned int*)((char*)d_ws + 15185920);
    float2*         sc1 = (float2*)((char*)d_ws + 17676288);
    unsigned short* w2c = (unsigned short*)((char*)d_ws + 17678720);

    const int prep_elems = WBROWS * WROW + BATCH * 4 * LIN + MTN * 16 + NU * NP * LDKW;
    k_prep<<<(prep_elems + 255) / 256, 256, 0, stream>>>(
        w1, x, b1, g1, be1, m1, v1, w2, Wbh, Wbl, xc, sc1, w2c);

    dim3 gc(BATCH, 6);
    k_conv7d<<<gc, 512, 0, stream>>>(Wbh, Wbl, xc, sc1, ypool);

    dim3 gm(NU, 2);
    k_mlp<<<gm, 256, 0, stream>>>(ypool, w2c, g2, b2, be2, m2, v2,
                                  w3, b3, g3, be3, m3, v3, zbuf);

    dim3 gf(NCLS, 4);
    k_final<<<gf, 256, 0, stream>>>(zbuf, wf, bf, (float*)d_out);
}

// Round 9
// 151.535 us; speedup vs baseline: 1.4260x; 1.0116x over previous
//
#include <hip/hip_runtime.h>
#include <hip/hip_bf16.h>

#define BATCH    256
#define NU       300
#define LIN      608
#define FILT     19
#define LPOOL    84
#define POOL     7
#define HID      100
#define NCLS     50
#define EPS      1e-5f
#define KP       96    // k extent of stage-2 (84 -> 96 padded)
#define NP       112   // stage-2 N padded (100 -> 112)
#define LDK      104   // conv LDS row stride (shorts)
#define LDKW     96    // w2c row stride (shorts)
#define WROW     104   // packed-W row stride (shorts)
#define WBROWS   320   // packed-W rows (300 + pad)
#define TCHUNK   112   // t per conv block = lcm(16,7)
#define MTN      19    // conv u-tiles (rows 0..303 cover u<300)
#define CSTR     116   // conv epilogue scratch stride (floats); (CSTR/4)%8=5 -> quad-spread

typedef __attribute__((ext_vector_type(8))) short short8;   // 8 bf16
typedef __attribute__((ext_vector_type(4))) float float4v;  // MFMA acc
typedef __attribute__((ext_vector_type(4))) unsigned short us4; // 4 bf16 out

// same-wave LDS producer->consumer ordering: lgkmcnt(0) ONLY.
#define LDS_WAIT() __asm__ __volatile__("s_waitcnt lgkmcnt(0)" ::: "memory")

__device__ __forceinline__ unsigned short f2bf(float f) {
    unsigned u = __float_as_uint(f);
    u += 0x7fffu + ((u >> 16) & 1u);       // round-to-nearest-even
    return (unsigned short)(u >> 16);
}
__device__ __forceinline__ float bf2f(unsigned short h) {
    return __uint_as_float(((unsigned)h) << 16);
}

// ---------------------------------------------------------------------------
// k_prep v3: (byte-identical to R5 — verified at 149.1)
// ---------------------------------------------------------------------------
__global__ void k_prep(const float* __restrict__ w1, const float* __restrict__ x,
                       const float* __restrict__ b1, const float* __restrict__ g1,
                       const float* __restrict__ be1, const float* __restrict__ m1,
                       const float* __restrict__ v1, const float* __restrict__ w2,
                       unsigned short* __restrict__ Wbh,
                       unsigned short* __restrict__ Wbl,
                       unsigned int* __restrict__ xc,
                       float2* __restrict__ s1c1,
                       unsigned short* __restrict__ w2c)
{
    const int idx = blockIdx.x * 256 + threadIdx.x;
    const int NW = WBROWS * WROW;               // 33280
    if (idx < NW) {
        const int u = idx / WROW, kk = idx - u * WROW;
        float wv = 0.f;
        if (u < NU && kk < 96) {
            const int c = kk / 24, tap = kk - 24 * c;
            if (tap < FILT) wv = w1[(u * 4 + c) * FILT + tap];
        }
        const unsigned short hi = f2bf(wv);
        Wbh[idx] = hi;
        Wbl[idx] = f2bf(wv - bf2f(hi));
    }
    const int j = idx - NW;
    if (j >= 0 && j < BATCH * 4 * LIN) {
        const float xv = x[j];
        const unsigned short hi = f2bf(xv);
        const unsigned short lo = f2bf(xv - bf2f(hi));
        xc[j] = (unsigned)hi | ((unsigned)lo << 16);
    }
    const int j2 = j - BATCH * 4 * LIN;
    if (j2 >= 0 && j2 < MTN * 16) {
        float2 v = {0.f, 0.f};
        if (j2 < NU) {
            const float s = g1[j2] * rsqrtf(v1[j2] + EPS);
            v.x = s;
            v.y = (b1[j2] - m1[j2]) * s + be1[j2];
        }
        s1c1[j2] = v;
    }
    const int j3 = j2 - MTN * 16;
    if (j3 >= 0 && j3 < NU * NP * LDKW) {
        const int u  = j3 / (NP * LDKW);
        const int r  = j3 - u * (NP * LDKW);
        const int o  = r / LDKW;
        const int kc = r - o * LDKW;
        float wv = 0.f;
        if (o < HID && kc < LPOOL) wv = w2[((size_t)u * HID + o) * LPOOL + kc];
        w2c[j3] = f2bf(wv);
    }
}

// ---------------------------------------------------------------------------
// k_conv7d v9: R5's verified v5 (256 thr / 4 waves / paired tiles / 5-5-5-4),
//   ONE change — COALESCED ypool layout [b][tc][u][16]:
//   R7 falsified the residency theory (more waves never help: R2, R7).
//   Remaining shared-serial suspect: store path. Old [b][u][pg] wave-store
//   touched 16 partial lines (192B u-stride), each 64B line co-owned by two
//   tc-blocks (cross-XCD RFO; R6 measured 3x write amplification, 45MB vs
//   14.7 payload). New layout: per (b,tc,tile) the wave writes lane*8B —
//   one contiguous 512B burst, 8 full lines, zero line sharing.
//   Epilogue lane remap (u_l,wq)=(lane>>2,lane&3) keeps the Cs-read
//   bank-group spread (5u+7wq+r)%8 identical. tc=5/wq>=1 lanes store 0 =
//   the k-pad zeros mlp expects. Same workspace bytes.
// ---------------------------------------------------------------------------
__global__ __launch_bounds__(256, 3)
void k_conv7d(const unsigned short* __restrict__ Wbh,
              const unsigned short* __restrict__ Wbl,
              const unsigned int* __restrict__ xc,
              const float2* __restrict__ s1c1,
              unsigned short* __restrict__ ypool)
{
    __shared__ __align__(16) unsigned short Bh[TCHUNK * LDK];  // 23296 B
    __shared__ __align__(16) float Cs[4][16 * CSTR];           // 29696 B (per-wave)

    const int tid = threadIdx.x;
    const int b   = blockIdx.x;
    const int tc  = blockIdx.y;
    const int t0  = TCHUNK * tc;
    const int NT  = (tc == 5) ? 2 : 7;         // N-tiles (t) in this block

    // ---- stage B tile (im2col, hi only), plane-major (R5 mapping) ----
    for (int i = tid; i < 12 * TCHUNK; i += 256) {
        const int plane = i / TCHUNK;          // 0..11 = third*4 + c
        const int trow  = i - plane * TCHUNK;
        if (trow >= 16 * NT) continue;         // unused rows (tc==5)
        const int third = plane >> 2;          // 0..2
        const int c     = plane & 3;           // 0..3
        const int kkb   = 24 * c + 8 * third;
        const int tt0   = t0 + trow + 8 * third;
        const unsigned int* src = xc + ((b * 4 + c) * LIN + tt0);

        unsigned int w[8];
        if (third < 2 && tt0 + 8 <= LIN) {     // all 8 taps valid & in range
            const uint4 v0 = *(const uint4*)(src);
            const uint4 v1 = *(const uint4*)(src + 4);
            w[0] = v0.x; w[1] = v0.y; w[2] = v0.z; w[3] = v0.w;
            w[4] = v1.x; w[5] = v1.y; w[6] = v1.z; w[7] = v1.w;
        } else {
#pragma unroll
            for (int j = 0; j < 8; ++j) {
                const int tap = 8 * third + j;
                const int tt  = tt0 + j;
                unsigned int v = 0;
                if (tap < FILT && tt < LIN) v = src[j];
                w[j] = v;
            }
        }
        short8 hv;
#pragma unroll
        for (int j = 0; j < 8; ++j) hv[j] = (short)(w[j] & 0xffffu);
        *(short8*)(&Bh[trow * LDK + kkb]) = hv;
    }
    __syncthreads();   // the ONLY block-wide barrier

    const int lane = tid & 63;
    const int n    = lane & 15;
    const int quad = lane >> 4;
    const int wave = tid >> 6;
    float* Csw = Cs[wave];          // wave-private transposed scratch [16][CSTR]

    // epilogue lane map for coalesced stores: addr = lane*8B within 512B slab
    const int u_l = lane >> 2;      // u row within tile (0..15)
    const int wq  = lane & 3;       // window quad (0..3)
    const int pg0 = 16 * tc + 4 * wq;

    // contiguous tile ranges: wave w owns tiles [5w, min(5w+5,19))
    const int jend = 5 * wave + ((wave == 3) ? 4 : 5);
    for (int mt0 = 5 * wave; mt0 < jend; mt0 += 2) {
        const bool two = (mt0 + 1 < jend);

        // ---- W fragments (hi & lo) for both tiles, from global (L2-hot) ----
        short8 a0h[3], a0l[3], a1h[3], a1l[3];
        {
            const unsigned short* wrh = Wbh + (size_t)(mt0 * 16 + n) * WROW;
            const unsigned short* wrl = Wbl + (size_t)(mt0 * 16 + n) * WROW;
#pragma unroll
            for (int s = 0; s < 3; ++s) {
                a0h[s] = *(const short8*)(wrh + 32 * s + 8 * quad);
                a0l[s] = *(const short8*)(wrl + 32 * s + 8 * quad);
            }
            const int m1r = two ? (mt0 + 1) : mt0;
            const unsigned short* wrh1 = Wbh + (size_t)(m1r * 16 + n) * WROW;
            const unsigned short* wrl1 = Wbl + (size_t)(m1r * 16 + n) * WROW;
#pragma unroll
            for (int s = 0; s < 3; ++s) {
                a1h[s] = *(const short8*)(wrh1 + 32 * s + 8 * quad);
                a1l[s] = *(const short8*)(wrl1 + 32 * s + 8 * quad);
            }
        }

        // ---- main loop: xh-frags read once per nt, used by BOTH tiles ----
        // SWAPPED operands: acc = x_tile(16t x 32k) * W^T(32k x 16u) -> D[t][u]
        float4v acc[2][7];
#pragma unroll
        for (int t2 = 0; t2 < 2; ++t2)
#pragma unroll
            for (int nt = 0; nt < 7; ++nt)
                acc[t2][nt] = (float4v){0.f, 0.f, 0.f, 0.f};

#pragma unroll
        for (int nt = 0; nt < 7; ++nt) {
            if (nt < NT) {
                short8 bhf[3];
#pragma unroll
                for (int s = 0; s < 3; ++s)
                    bhf[s] = *(const short8*)(&Bh[(16 * nt + n) * LDK + 32 * s + 8 * quad]);
#pragma unroll
                for (int s = 0; s < 3; ++s)
                    acc[0][nt] = __builtin_amdgcn_mfma_f32_16x16x32_bf16(
                        bhf[s], a0h[s], acc[0][nt], 0, 0, 0);
#pragma unroll
                for (int s = 0; s < 3; ++s)
                    acc[0][nt] = __builtin_amdgcn_mfma_f32_16x16x32_bf16(
                        bhf[s], a0l[s], acc[0][nt], 0, 0, 0);
                if (two) {
#pragma unroll
                    for (int s = 0; s < 3; ++s)
                        acc[1][nt] = __builtin_amdgcn_mfma_f32_16x16x32_bf16(
                            bhf[s], a1h[s], acc[1][nt], 0, 0, 0);
#pragma unroll
                    for (int s = 0; s < 3; ++s)
                        acc[1][nt] = __builtin_amdgcn_mfma_f32_16x16x32_bf16(
                            bhf[s], a1l[s], acc[1][nt], 0, 0, 0);
                }
            }
        }

        // ---- wave-local epilogue per tile: write Cs, b128 reads, 8B store ----
#pragma unroll
        for (int t2 = 0; t2 < 2; ++t2) {
            if (t2 == 1 && !two) break;
            const int mt = mt0 + t2;

            LDS_WAIT();   // WAR: previous tile's pool reads complete
            // lane owns u=n, t=16*nt+4*quad+r : one b128 per nt (all lanes)
#pragma unroll
            for (int nt = 0; nt < 7; ++nt) {
                if (nt < NT)
                    *(float4v*)(&Csw[n * CSTR + 16 * nt + 4 * quad]) = acc[t2][nt];
            }
            LDS_WAIT();   // RAW: writes visible to all lanes of this wave

            // lane (u_l, wq): read 28-float span t=[28wq, 28wq+28) of row u_l
            float rv[28];
#pragma unroll
            for (int r7 = 0; r7 < 7; ++r7)
                *(float4v*)(&rv[4 * r7]) =
                    *(const float4v*)(&Csw[u_l * CSTR + 28 * wq + 4 * r7]);

            const int uglob = mt * 16 + u_l;
            const float2 sc = s1c1[uglob];     // s1c1 sized 304 >= max uglob+1
            us4 pk;
#pragma unroll
            for (int w4 = 0; w4 < 4; ++w4) {
                const int pg = pg0 + w4;
                unsigned short ov = 0;
                if (pg < LPOOL) {
                    float m0 = fmaxf(rv[7 * w4 + 0], rv[7 * w4 + 1]);
                    float m1 = fmaxf(rv[7 * w4 + 2], rv[7 * w4 + 3]);
                    float m2 = fmaxf(rv[7 * w4 + 4], rv[7 * w4 + 5]);
                    m0 = fmaxf(m0, rv[7 * w4 + 6]);
                    ov = f2bf(__expf(fmaf(fmaxf(fmaxf(m0, m1), m2), sc.x, sc.y)));
                }
                pk[w4] = ov;
            }
            // ypool2[b][tc][u][16]: wave writes one contiguous 512B slab
            if (uglob < NU)
                *(us4*)(&ypool[(((size_t)b * 6 + tc) * NU + uglob) * 16 + 4 * wq]) = pk;
        }
    }
}

// ---------------------------------------------------------------------------
// k_mlp v8: R5's v6 (global-direct fragments, A-reuse across 2 batch groups)
//   with B-fragment addressing for the ypool2 [b][tc][u][16] layout:
//   k-chunk c = kk/16 lives at ((bb*6 + c)*NU + u)*16 + kk%16.
// ---------------------------------------------------------------------------
__global__ __launch_bounds__(256, 4)
void k_mlp(const unsigned short* __restrict__ ypool,
           const unsigned short* __restrict__ w2c,
           const float* __restrict__ g2, const float* __restrict__ b2,
           const float* __restrict__ be2, const float* __restrict__ m2,
           const float* __restrict__ v2,
           const float* __restrict__ w3, const float* __restrict__ b3,
           const float* __restrict__ g3, const float* __restrict__ be3,
           const float* __restrict__ m3, const float* __restrict__ v3,
           float* __restrict__ zbuf)
{
    __shared__ __align__(16) float4 cs4[NP];                // (s2,c2,w3,0)

    const int tid = threadIdx.x;
    const int u   = blockIdx.x;
    const int b0  = blockIdx.y * 128;

    if (tid < NP) {
        float4 cv = {0.f, 0.f, 0.f, 0.f};
        if (tid < HID) {
            const int uo = u * HID + tid;
            const float s = g2[uo] * rsqrtf(v2[uo] + EPS);
            cv.x = s;
            cv.y = (b2[uo] - m2[uo]) * s + be2[uo];
            cv.z = w3[uo];
        }
        cs4[tid] = cv;
    }
    __syncthreads();

    const int lane = tid & 63;
    const int wave = tid >> 6;
    const int col  = lane & 15;
    const int quad = lane >> 4;
    const int bbA  = b0 + 16 * wave + col;          // batch group 0
    const int bbB  = bbA + 64;                       // batch group 1

    // B fragments: kk0 = 32s+8quad -> chunk 2s+(quad>>1), offset 8*(quad&1)
    short8 bfA[3], bfB[3];
#pragma unroll
    for (int s = 0; s < 3; ++s) {
        const int ck = 2 * s + (quad >> 1);
        const int of = 8 * (quad & 1);
        bfA[s] = *(const short8*)(ypool + (((size_t)bbA * 6 + ck) * NU + u) * 16 + of);
        bfB[s] = *(const short8*)(ypool + (((size_t)bbB * 6 + ck) * NU + u) * 16 + of);
    }

    const unsigned short* wbase = w2c + (size_t)u * (NP * LDKW);
    float zpA = 0.f, zpB = 0.f;
#pragma unroll
    for (int mt = 0; mt < 7; ++mt) {
        short8 af[3];
#pragma unroll
        for (int s = 0; s < 3; ++s)
            af[s] = *(const short8*)(wbase + (16 * mt + col) * LDKW + 32 * s + 8 * quad);

        float4v a0 = {0.f, 0.f, 0.f, 0.f}, a1 = {0.f, 0.f, 0.f, 0.f};
#pragma unroll
        for (int s = 0; s < 3; ++s) {
            a0 = __builtin_amdgcn_mfma_f32_16x16x32_bf16(af[s], bfA[s], a0, 0, 0, 0);
            a1 = __builtin_amdgcn_mfma_f32_16x16x32_bf16(af[s], bfB[s], a1, 0, 0, 0);
        }
#pragma unroll
        for (int r = 0; r < 4; ++r) {
            const float4 cv = cs4[16 * mt + 4 * quad + r];
            zpA = fmaf(fmaxf(fmaf(a0[r], cv.x, cv.y), 0.f), cv.z, zpA);
            zpB = fmaf(fmaxf(fmaf(a1[r], cv.x, cv.y), 0.f), cv.z, zpB);
        }
    }

    zpA += __shfl_xor(zpA, 16); zpA += __shfl_xor(zpA, 32);
    zpB += __shfl_xor(zpB, 16); zpB += __shfl_xor(zpB, 32);

    if (quad == 0) {
        const float s3 = g3[u] * rsqrtf(v3[u] + EPS);
        const float c3 = (b3[u] - m3[u]) * s3 + be3[u];
        zbuf[(size_t)u * BATCH + bbA] = fmaxf(fmaf(zpA, s3, c3), 0.f);
        zbuf[(size_t)u * BATCH + bbB] = fmaxf(fmaf(zpB, s3, c3), 0.f);
    }
}

// ---------------------------------------------------------------------------
// k_final v2: (byte-identical to R11-R24)
// ---------------------------------------------------------------------------
__global__ __launch_bounds__(256, 4)
void k_final(const float* __restrict__ zbuf, const float* __restrict__ wf,
             const float* __restrict__ bf, float* __restrict__ out)
{
    __shared__ float red[4][64];
    const int nc   = blockIdx.x;
    const int bq   = blockIdx.y;
    const int lane = threadIdx.x & 63;
    const int wave = threadIdx.x >> 6;
    const int b    = bq * 64 + lane;

    float a0 = 0.f, a1 = 0.f, a2 = 0.f;
    const int u0 = wave * 75;
#pragma unroll 5
    for (int i = 0; i < 75; i += 3) {
        a0 = fmaf(zbuf[(size_t)(u0 + i + 0) * BATCH + b], wf[nc * NU + u0 + i + 0], a0);
        a1 = fmaf(zbuf[(size_t)(u0 + i + 1) * BATCH + b], wf[nc * NU + u0 + i + 1], a1);
        a2 = fmaf(zbuf[(size_t)(u0 + i + 2) * BATCH + b], wf[nc * NU + u0 + i + 2], a2);
    }
    red[wave][lane] = (a0 + a1) + a2;
    __syncthreads();
    if (threadIdx.x < 64) {
        const float s = (red[0][lane] + red[1][lane]) + (red[2][lane] + red[3][lane]);
        out[(size_t)b * NCLS + nc] = s + bf[nc];
    }
}

extern "C" void kernel_launch(void* const* d_in, const int* in_sizes, int n_in,
                              void* d_out, int out_size, void* d_ws, size_t ws_size,
                              hipStream_t stream)
{
    const float* x   = (const float*)d_in[0];
    const float* w1  = (const float*)d_in[1];
    const float* b1  = (const float*)d_in[2];
    const float* g1  = (const float*)d_in[3];
    const float* be1 = (const float*)d_in[4];
    const float* m1  = (const float*)d_in[5];
    const float* v1  = (const float*)d_in[6];
    const float* w2  = (const float*)d_in[7];
    const float* b2  = (const float*)d_in[8];
    const float* g2  = (const float*)d_in[9];
    const float* be2 = (const float*)d_in[10];
    const float* m2  = (const float*)d_in[11];
    const float* v2  = (const float*)d_in[12];
    const float* w3  = (const float*)d_in[13];
    const float* b3  = (const float*)d_in[14];
    const float* g3  = (const float*)d_in[15];
    const float* be3 = (const float*)d_in[16];
    const float* m3  = (const float*)d_in[17];
    const float* v3  = (const float*)d_in[18];
    const float* wf  = (const float*)d_in[19];
    const float* bf  = (const float*)d_in[20];

    // workspace layout (bytes):
    //   ypool  bf16 [256][6][300][16] @ 0          (14,745,600)  [b][tc][u][16]
    //   zbuf   f32  [300][256]        @ 14,745,600 (307,200)
    //   Wbh    bf16 [320][104]        @ 15,052,800 (66,560)
    //   Wbl    bf16 [320][104]        @ 15,119,360 (66,560)
    //   xc     u32  [256][4][608]     @ 15,185,920 (2,490,368)
    //   s1c1   f32x2 [304]            @ 17,676,288 (2,432)
    //   w2c    bf16 [300][112][96]    @ 17,678,720 (6,451,200)
    unsigned short* ypool = (unsigned short*)d_ws;
    float* zbuf = (float*)((char*)d_ws + 14745600);
    unsigned short* Wbh = (unsigned short*)((char*)d_ws + 15052800);
    unsigned short* Wbl = (unsigned short*)((char*)d_ws + 15119360);
    unsigned int*   xc  = (unsigned int*)((char*)d_ws + 15185920);
    float2*         sc1 = (float2*)((char*)d_ws + 17676288);
    unsigned short* w2c = (unsigned short*)((char*)d_ws + 17678720);

    const int prep_elems = WBROWS * WROW + BATCH * 4 * LIN + MTN * 16 + NU * NP * LDKW;
    k_prep<<<(prep_elems + 255) / 256, 256, 0, stream>>>(
        w1, x, b1, g1, be1, m1, v1, w2, Wbh, Wbl, xc, sc1, w2c);

    dim3 gc(BATCH, 6);
    k_conv7d<<<gc, 256, 0, stream>>>(Wbh, Wbl, xc, sc1, ypool);

    dim3 gm(NU, 2);
    k_mlp<<<gm, 256, 0, stream>>>(ypool, w2c, g2, b2, be2, m2, v2,
                                  w3, b3, g3, be3, m3, v3, zbuf);

    dim3 gf(NCLS, 4);
    k_final<<<gf, 256, 0, stream>>>(zbuf, wf, bf, (float*)d_out);
}

// Round 10
// 148.403 us; speedup vs baseline: 1.4561x; 1.0211x over previous
//
#include <hip/hip_runtime.h>
#include <hip/hip_bf16.h>

#define BATCH    256
#define NU       300
#define LIN      608
#define FILT     19
#define LPOOL    84
#define POOL     7
#define HID      100
#define NCLS     50
#define EPS      1e-5f
#define KP       96    // stage-2 K padded (84 -> 96)
#define NP       112   // stage-2 N padded (100 -> 112)
#define LDK      104   // conv LDS row stride (shorts)
#define LDKW     96    // w2c row stride (shorts)
#define WROW     104   // packed-W row stride (shorts)
#define WBROWS   320   // packed-W rows (300 + pad)
#define TCHUNK   112   // t per conv block = lcm(16,7)
#define MTN      19    // conv u-tiles (rows 0..303 cover u<300)
#define CSTR     116   // conv epilogue scratch stride (floats); (CSTR/4)%8=5 -> quad-spread

typedef __attribute__((ext_vector_type(8))) short short8;   // 8 bf16
typedef __attribute__((ext_vector_type(4))) float float4v;  // MFMA acc
typedef __attribute__((ext_vector_type(4))) unsigned short us4; // 4 bf16 out

// same-wave LDS producer->consumer ordering: lgkmcnt(0) ONLY.
#define LDS_WAIT() __asm__ __volatile__("s_waitcnt lgkmcnt(0)" ::: "memory")

__device__ __forceinline__ unsigned short f2bf(float f) {
    unsigned u = __float_as_uint(f);
    u += 0x7fffu + ((u >> 16) & 1u);       // round-to-nearest-even
    return (unsigned short)(u >> 16);
}
__device__ __forceinline__ float bf2f(unsigned short h) {
    return __uint_as_float(((unsigned)h) << 16);
}

// ---------------------------------------------------------------------------
// k_prep v3: (byte-identical to R5 — verified at 149.1)
// ---------------------------------------------------------------------------
__global__ void k_prep(const float* __restrict__ w1, const float* __restrict__ x,
                       const float* __restrict__ b1, const float* __restrict__ g1,
                       const float* __restrict__ be1, const float* __restrict__ m1,
                       const float* __restrict__ v1, const float* __restrict__ w2,
                       unsigned short* __restrict__ Wbh,
                       unsigned short* __restrict__ Wbl,
                       unsigned int* __restrict__ xc,
                       float2* __restrict__ s1c1,
                       unsigned short* __restrict__ w2c)
{
    const int idx = blockIdx.x * 256 + threadIdx.x;
    const int NW = WBROWS * WROW;               // 33280
    if (idx < NW) {
        const int u = idx / WROW, kk = idx - u * WROW;
        float wv = 0.f;
        if (u < NU && kk < 96) {
            const int c = kk / 24, tap = kk - 24 * c;
            if (tap < FILT) wv = w1[(u * 4 + c) * FILT + tap];
        }
        const unsigned short hi = f2bf(wv);
        Wbh[idx] = hi;
        Wbl[idx] = f2bf(wv - bf2f(hi));
    }
    const int j = idx - NW;
    if (j >= 0 && j < BATCH * 4 * LIN) {
        const float xv = x[j];
        const unsigned short hi = f2bf(xv);
        const unsigned short lo = f2bf(xv - bf2f(hi));
        xc[j] = (unsigned)hi | ((unsigned)lo << 16);
    }
    const int j2 = j - BATCH * 4 * LIN;
    if (j2 >= 0 && j2 < MTN * 16) {
        float2 v = {0.f, 0.f};
        if (j2 < NU) {
            const float s = g1[j2] * rsqrtf(v1[j2] + EPS);
            v.x = s;
            v.y = (b1[j2] - m1[j2]) * s + be1[j2];
        }
        s1c1[j2] = v;
    }
    const int j3 = j2 - MTN * 16;
    if (j3 >= 0 && j3 < NU * NP * LDKW) {
        const int u  = j3 / (NP * LDKW);
        const int r  = j3 - u * (NP * LDKW);
        const int o  = r / LDKW;
        const int kc = r - o * LDKW;
        float wv = 0.f;
        if (o < HID && kc < LPOOL) wv = w2[((size_t)u * HID + o) * LPOOL + kc];
        w2c[j3] = f2bf(wv);
    }
}

// ---------------------------------------------------------------------------
// k_conv7d v5: (byte-identical to R5 — best measured config, 149.1 twice)
//   256 thr / 4 waves, paired tiles, contiguous 5/5/5/4 ranges, plane-major
//   staging, D[t][u] via swapped MFMA operands, full Cs + 2 lgkm waits/tile,
//   packed 8B ypool stores in [b][u][pg] layout.
//   Falsified alternatives (do NOT revisit): more waves (R2,R7), halved-Cs
//   +z-split (R2), [b][tc][u][16] store layout (R9), inline W/x (R6).
// ---------------------------------------------------------------------------
__global__ __launch_bounds__(256, 3)
void k_conv7d(const unsigned short* __restrict__ Wbh,
              const unsigned short* __restrict__ Wbl,
              const unsigned int* __restrict__ xc,
              const float2* __restrict__ s1c1,
              unsigned short* __restrict__ ypool)
{
    __shared__ __align__(16) unsigned short Bh[TCHUNK * LDK];  // 23296 B
    __shared__ __align__(16) float Cs[4][16 * CSTR];           // 29696 B (per-wave)

    const int tid = threadIdx.x;
    const int b   = blockIdx.x;
    const int tc  = blockIdx.y;
    const int t0  = TCHUNK * tc;
    const int NT  = (tc == 5) ? 2 : 7;         // N-tiles (t) in this block

    // ---- stage B tile (im2col, hi only), plane-major for coalescing ----
    for (int i = tid; i < 12 * TCHUNK; i += 256) {
        const int plane = i / TCHUNK;          // 0..11 = third*4 + c
        const int trow  = i - plane * TCHUNK;
        if (trow >= 16 * NT) continue;         // unused rows (tc==5)
        const int third = plane >> 2;          // 0..2
        const int c     = plane & 3;           // 0..3
        const int kkb   = 24 * c + 8 * third;
        const int tt0   = t0 + trow + 8 * third;
        const unsigned int* src = xc + ((b * 4 + c) * LIN + tt0);

        unsigned int w[8];
        if (third < 2 && tt0 + 8 <= LIN) {     // all 8 taps valid & in range
            const uint4 v0 = *(const uint4*)(src);
            const uint4 v1 = *(const uint4*)(src + 4);
            w[0] = v0.x; w[1] = v0.y; w[2] = v0.z; w[3] = v0.w;
            w[4] = v1.x; w[5] = v1.y; w[6] = v1.z; w[7] = v1.w;
        } else {
#pragma unroll
            for (int j = 0; j < 8; ++j) {
                const int tap = 8 * third + j;
                const int tt  = tt0 + j;
                unsigned int v = 0;
                if (tap < FILT && tt < LIN) v = src[j];
                w[j] = v;
            }
        }
        short8 hv;
#pragma unroll
        for (int j = 0; j < 8; ++j) hv[j] = (short)(w[j] & 0xffffu);
        *(short8*)(&Bh[trow * LDK + kkb]) = hv;
    }
    __syncthreads();   // the ONLY block-wide barrier

    const int lane = tid & 63;
    const int n    = lane & 15;
    const int quad = lane >> 4;
    const int wave = tid >> 6;
    float* Csw = Cs[wave];          // wave-private transposed scratch [16][CSTR]

    const int u_l = lane & 15;      // epilogue: u row within tile
    const int wq  = lane >> 4;      // epilogue: window quad -> pg0 = 16tc+4wq
    const int pg0 = 16 * tc + 4 * wq;

    // contiguous tile ranges: wave w owns tiles [5w, min(5w+5,19))
    const int jend = 5 * wave + ((wave == 3) ? 4 : 5);
    for (int mt0 = 5 * wave; mt0 < jend; mt0 += 2) {
        const bool two = (mt0 + 1 < jend);

        // ---- W fragments (hi & lo) for both tiles, from global (L2-hot) ----
        short8 a0h[3], a0l[3], a1h[3], a1l[3];
        {
            const unsigned short* wrh = Wbh + (size_t)(mt0 * 16 + n) * WROW;
            const unsigned short* wrl = Wbl + (size_t)(mt0 * 16 + n) * WROW;
#pragma unroll
            for (int s = 0; s < 3; ++s) {
                a0h[s] = *(const short8*)(wrh + 32 * s + 8 * quad);
                a0l[s] = *(const short8*)(wrl + 32 * s + 8 * quad);
            }
            const int m1r = two ? (mt0 + 1) : mt0;
            const unsigned short* wrh1 = Wbh + (size_t)(m1r * 16 + n) * WROW;
            const unsigned short* wrl1 = Wbl + (size_t)(m1r * 16 + n) * WROW;
#pragma unroll
            for (int s = 0; s < 3; ++s) {
                a1h[s] = *(const short8*)(wrh1 + 32 * s + 8 * quad);
                a1l[s] = *(const short8*)(wrl1 + 32 * s + 8 * quad);
            }
        }

        // ---- main loop: xh-frags read once per nt, used by BOTH tiles ----
        // SWAPPED operands: acc = x_tile(16t x 32k) * W^T(32k x 16u) -> D[t][u]
        float4v acc[2][7];
#pragma unroll
        for (int t2 = 0; t2 < 2; ++t2)
#pragma unroll
            for (int nt = 0; nt < 7; ++nt)
                acc[t2][nt] = (float4v){0.f, 0.f, 0.f, 0.f};

#pragma unroll
        for (int nt = 0; nt < 7; ++nt) {
            if (nt < NT) {
                short8 bhf[3];
#pragma unroll
                for (int s = 0; s < 3; ++s)
                    bhf[s] = *(const short8*)(&Bh[(16 * nt + n) * LDK + 32 * s + 8 * quad]);
#pragma unroll
                for (int s = 0; s < 3; ++s)
                    acc[0][nt] = __builtin_amdgcn_mfma_f32_16x16x32_bf16(
                        bhf[s], a0h[s], acc[0][nt], 0, 0, 0);
#pragma unroll
                for (int s = 0; s < 3; ++s)
                    acc[0][nt] = __builtin_amdgcn_mfma_f32_16x16x32_bf16(
                        bhf[s], a0l[s], acc[0][nt], 0, 0, 0);
                if (two) {
#pragma unroll
                    for (int s = 0; s < 3; ++s)
                        acc[1][nt] = __builtin_amdgcn_mfma_f32_16x16x32_bf16(
                            bhf[s], a1h[s], acc[1][nt], 0, 0, 0);
#pragma unroll
                    for (int s = 0; s < 3; ++s)
                        acc[1][nt] = __builtin_amdgcn_mfma_f32_16x16x32_bf16(
                            bhf[s], a1l[s], acc[1][nt], 0, 0, 0);
                }
            }
        }

        // ---- wave-local epilogue per tile: write Cs, b128 reads, 8B store ----
#pragma unroll
        for (int t2 = 0; t2 < 2; ++t2) {
            if (t2 == 1 && !two) break;
            const int mt = mt0 + t2;

            LDS_WAIT();   // WAR: previous tile's pool reads complete
            // lane owns u=n, t=16*nt+4*quad+r : one b128 per nt (all lanes)
#pragma unroll
            for (int nt = 0; nt < 7; ++nt) {
                if (nt < NT)
                    *(float4v*)(&Csw[n * CSTR + 16 * nt + 4 * quad]) = acc[t2][nt];
            }
            LDS_WAIT();   // RAW: writes visible to all lanes of this wave

            // lane (u_l, wq): read 28-float span t=[28wq, 28wq+28) of row u_l
            float rv[28];
#pragma unroll
            for (int r7 = 0; r7 < 7; ++r7)
                *(float4v*)(&rv[4 * r7]) =
                    *(const float4v*)(&Csw[u_l * CSTR + 28 * wq + 4 * r7]);

            const int uglob = mt * 16 + u_l;
            const float2 sc = s1c1[uglob];     // s1c1 sized 304 >= max uglob+1
            us4 pk;
#pragma unroll
            for (int w4 = 0; w4 < 4; ++w4) {
                const int pg = pg0 + w4;
                unsigned short ov = 0;
                if (pg < LPOOL) {
                    float m0 = fmaxf(rv[7 * w4 + 0], rv[7 * w4 + 1]);
                    float m1 = fmaxf(rv[7 * w4 + 2], rv[7 * w4 + 3]);
                    float m2 = fmaxf(rv[7 * w4 + 4], rv[7 * w4 + 5]);
                    m0 = fmaxf(m0, rv[7 * w4 + 6]);
                    ov = f2bf(__expf(fmaf(fmaxf(fmaxf(m0, m1), m2), sc.x, sc.y)));
                }
                pk[w4] = ov;
            }
            if (uglob < NU)
                *(us4*)(&ypool[((size_t)b * NU + uglob) * KP + pg0]) = pk;
        }
    }
}

// ---------------------------------------------------------------------------
// k_mlp v6: (byte-identical to R5 — verified at 149.1)
//   Global-direct fragments (no LDS staging) + A-fragment reuse across two
//   16-batch groups per wave. Grid (300, 2).
// ---------------------------------------------------------------------------
__global__ __launch_bounds__(256, 4)
void k_mlp(const unsigned short* __restrict__ ypool,
           const unsigned short* __restrict__ w2c,
           const float* __restrict__ g2, const float* __restrict__ b2,
           const float* __restrict__ be2, const float* __restrict__ m2,
           const float* __restrict__ v2,
           const float* __restrict__ w3, const float* __restrict__ b3,
           const float* __restrict__ g3, const float* __restrict__ be3,
           const float* __restrict__ m3, const float* __restrict__ v3,
           float* __restrict__ zbuf)
{
    __shared__ __align__(16) float4 cs4[NP];                // (s2,c2,w3,0)

    const int tid = threadIdx.x;
    const int u   = blockIdx.x;
    const int b0  = blockIdx.y * 128;

    if (tid < NP) {
        float4 cv = {0.f, 0.f, 0.f, 0.f};
        if (tid < HID) {
            const int uo = u * HID + tid;
            const float s = g2[uo] * rsqrtf(v2[uo] + EPS);
            cv.x = s;
            cv.y = (b2[uo] - m2[uo]) * s + be2[uo];
            cv.z = w3[uo];
        }
        cs4[tid] = cv;
    }
    __syncthreads();

    const int lane = tid & 63;
    const int wave = tid >> 6;
    const int col  = lane & 15;
    const int quad = lane >> 4;
    const int bbA  = b0 + 16 * wave + col;          // batch group 0
    const int bbB  = bbA + 64;                       // batch group 1

    // B fragments for both batch groups (192 B rows, read once)
    short8 bfA[3], bfB[3];
    {
        const unsigned short* yrA = ypool + ((size_t)bbA * NU + u) * KP;
        const unsigned short* yrB = ypool + ((size_t)bbB * NU + u) * KP;
#pragma unroll
        for (int s = 0; s < 3; ++s) {
            bfA[s] = *(const short8*)(yrA + 32 * s + 8 * quad);
            bfB[s] = *(const short8*)(yrB + 32 * s + 8 * quad);
        }
    }

    const unsigned short* wbase = w2c + (size_t)u * (NP * LDKW);
    float zpA = 0.f, zpB = 0.f;
#pragma unroll
    for (int mt = 0; mt < 7; ++mt) {
        short8 af[3];
#pragma unroll
        for (int s = 0; s < 3; ++s)
            af[s] = *(const short8*)(wbase + (16 * mt + col) * LDKW + 32 * s + 8 * quad);

        float4v a0 = {0.f, 0.f, 0.f, 0.f}, a1 = {0.f, 0.f, 0.f, 0.f};
#pragma unroll
        for (int s = 0; s < 3; ++s) {
            a0 = __builtin_amdgcn_mfma_f32_16x16x32_bf16(af[s], bfA[s], a0, 0, 0, 0);
            a1 = __builtin_amdgcn_mfma_f32_16x16x32_bf16(af[s], bfB[s], a1, 0, 0, 0);
        }
#pragma unroll
        for (int r = 0; r < 4; ++r) {
            const float4 cv = cs4[16 * mt + 4 * quad + r];
            zpA = fmaf(fmaxf(fmaf(a0[r], cv.x, cv.y), 0.f), cv.z, zpA);
            zpB = fmaf(fmaxf(fmaf(a1[r], cv.x, cv.y), 0.f), cv.z, zpB);
        }
    }

    zpA += __shfl_xor(zpA, 16); zpA += __shfl_xor(zpA, 32);
    zpB += __shfl_xor(zpB, 16); zpB += __shfl_xor(zpB, 32);

    if (quad == 0) {
        const float s3 = g3[u] * rsqrtf(v3[u] + EPS);
        const float c3 = (b3[u] - m3[u]) * s3 + be3[u];
        zbuf[(size_t)u * BATCH + bbA] = fmaxf(fmaf(zpA, s3, c3), 0.f);
        zbuf[(size_t)u * BATCH + bbB] = fmaxf(fmaf(zpB, s3, c3), 0.f);
    }
}

// ---------------------------------------------------------------------------
// k_final v2: (byte-identical to R11-R25)
// ---------------------------------------------------------------------------
__global__ __launch_bounds__(256, 4)
void k_final(const float* __restrict__ zbuf, const float* __restrict__ wf,
             const float* __restrict__ bf, float* __restrict__ out)
{
    __shared__ float red[4][64];
    const int nc   = blockIdx.x;
    const int bq   = blockIdx.y;
    const int lane = threadIdx.x & 63;
    const int wave = threadIdx.x >> 6;
    const int b    = bq * 64 + lane;

    float a0 = 0.f, a1 = 0.f, a2 = 0.f;
    const int u0 = wave * 75;
#pragma unroll 5
    for (int i = 0; i < 75; i += 3) {
        a0 = fmaf(zbuf[(size_t)(u0 + i + 0) * BATCH + b], wf[nc * NU + u0 + i + 0], a0);
        a1 = fmaf(zbuf[(size_t)(u0 + i + 1) * BATCH + b], wf[nc * NU + u0 + i + 1], a1);
        a2 = fmaf(zbuf[(size_t)(u0 + i + 2) * BATCH + b], wf[nc * NU + u0 + i + 2], a2);
    }
    red[wave][lane] = (a0 + a1) + a2;
    __syncthreads();
    if (threadIdx.x < 64) {
        const float s = (red[0][lane] + red[1][lane]) + (red[2][lane] + red[3][lane]);
        out[(size_t)b * NCLS + nc] = s + bf[nc];
    }
}

extern "C" void kernel_launch(void* const* d_in, const int* in_sizes, int n_in,
                              void* d_out, int out_size, void* d_ws, size_t ws_size,
                              hipStream_t stream)
{
    const float* x   = (const float*)d_in[0];
    const float* w1  = (const float*)d_in[1];
    const float* b1  = (const float*)d_in[2];
    const float* g1  = (const float*)d_in[3];
    const float* be1 = (const float*)d_in[4];
    const float* m1  = (const float*)d_in[5];
    const float* v1  = (const float*)d_in[6];
    const float* w2  = (const float*)d_in[7];
    const float* b2  = (const float*)d_in[8];
    const float* g2  = (const float*)d_in[9];
    const float* be2 = (const float*)d_in[10];
    const float* m2  = (const float*)d_in[11];
    const float* v2  = (const float*)d_in[12];
    const float* w3  = (const float*)d_in[13];
    const float* b3  = (const float*)d_in[14];
    const float* g3  = (const float*)d_in[15];
    const float* be3 = (const float*)d_in[16];
    const float* m3  = (const float*)d_in[17];
    const float* v3  = (const float*)d_in[18];
    const float* wf  = (const float*)d_in[19];
    const float* bf  = (const float*)d_in[20];

    // workspace layout (bytes):
    //   ypool  bf16 [256][300][96]  @ 0          (14,745,600)   [b][u][pg]
    //   zbuf   f32  [300][256]      @ 14,745,600 (307,200)
    //   Wbh    bf16 [320][104]      @ 15,052,800 (66,560)
    //   Wbl    bf16 [320][104]      @ 15,119,360 (66,560)
    //   xc     u32  [256][4][608]   @ 15,185,920 (2,490,368)
    //   s1c1   f32x2 [304]          @ 17,676,288 (2,432)
    //   w2c    bf16 [300][112][96]  @ 17,678,720 (6,451,200)
    unsigned short* ypool = (unsigned short*)d_ws;
    float* zbuf = (float*)((char*)d_ws + 14745600);
    unsigned short* Wbh = (unsigned short*)((char*)d_ws + 15052800);
    unsigned short* Wbl = (unsigned short*)((char*)d_ws + 15119360);
    unsigned int*   xc  = (unsigned int*)((char*)d_ws + 15185920);
    float2*         sc1 = (float2*)((char*)d_ws + 17676288);
    unsigned short* w2c = (unsigned short*)((char*)d_ws + 17678720);

    const int prep_elems = WBROWS * WROW + BATCH * 4 * LIN + MTN * 16 + NU * NP * LDKW;
    k_prep<<<(prep_elems + 255) / 256, 256, 0, stream>>>(
        w1, x, b1, g1, be1, m1, v1, w2, Wbh, Wbl, xc, sc1, w2c);

    dim3 gc(BATCH, 6);
    k_conv7d<<<gc, 256, 0, stream>>>(Wbh, Wbl, xc, sc1, ypool);

    dim3 gm(NU, 2);
    k_mlp<<<gm, 256, 0, stream>>>(ypool, w2c, g2, b2, be2, m2, v2,
                                  w3, b3, g3, be3, m3, v3, zbuf);

    dim3 gf(NCLS, 4);
    k_final<<<gf, 256, 0, stream>>>(zbuf, wf, bf, (float*)d_out);
}